// Round 9
// baseline (31.076 us; speedup 1.0000x reference)
//
#include <hip/hip_runtime.h>

#define FD 768
#define HD 256
#define NF 512
#define NC 512
#define PAIRS (NF * (NF - 1) / 2)   // 130816

typedef __attribute__((ext_vector_type(4))) float f32x4;
typedef __attribute__((ext_vector_type(8))) short bf16x8;

// RNE float->bf16, packed pair (a = low 16, b = high 16)
__device__ inline unsigned bf16pk(float a, float b) {
    unsigned ua = __float_as_uint(a), ub = __float_as_uint(b);
    ua = (ua + 0x7FFFu + ((ua >> 16) & 1u)) >> 16;
    ub = (ub + 0x7FFFu + ((ub >> 16) & 1u)) >> 16;
    return ua | (ub << 16);
}

// ---------------------------------------------------------------------------
// Kernel 0 (prep):
//   bid < 384:  Ebf[r][k] = bf16(E[r][k])  — linear, coalesced.
//   bid >= 384: Wt[c][k] = bf16(W1[k + (c<256?0:768)][c&255]) via LDS-tile
//     transpose (64k x 64c per block): coalesced f4 loads -> pitch-65 LDS
//     (write banks (kr+4c4+u)%32: 2-way; read banks (4kc+u+c)%32: 2-way)
//     -> coalesced 8B packed stores. No scattered global stores.
// ---------------------------------------------------------------------------
__global__ __launch_bounds__(256) void prep_kernel(
    const float* __restrict__ E, const float* __restrict__ W1,
    ushort* __restrict__ Ebf, ushort* __restrict__ Wt)
{
    const int bid = blockIdx.x, tid = threadIdx.x;
    if (bid < 384) {
        int idx = bid * 256 + tid;
        float4 v = ((const float4*)E)[idx];
        uint2 pk;
        pk.x = bf16pk(v.x, v.y);
        pk.y = bf16pk(v.z, v.w);
        *(uint2*)(Ebf + (size_t)idx * 4) = pk;
        return;
    }
    __shared__ float Ls[64 * 65];
    const int t = bid - 384;               // 0..191
    const int kt = t % 12, rest = t / 12;  // 12 k-tiles x (2 halves x 8 c-tiles)
    const int half = rest >> 3, ct = rest & 7;
    const int k0 = kt * 64, c0 = ct * 64;
    const int dofs = half ? FD : 0;

    const float4* W14 = (const float4*)W1;          // row pitch 64 f4
    #pragma unroll
    for (int s = 0; s < 4; ++s) {
        int idx = tid + 256 * s;                    // 1024 f4 tasks
        int kr = idx >> 4, c4 = idx & 15;
        float4 v = W14[(size_t)(dofs + k0 + kr) * 64 + (c0 >> 2) + c4];
        Ls[kr * 65 + 4 * c4 + 0] = v.x;
        Ls[kr * 65 + 4 * c4 + 1] = v.y;
        Ls[kr * 65 + 4 * c4 + 2] = v.z;
        Ls[kr * 65 + 4 * c4 + 3] = v.w;
    }
    __syncthreads();

    const int kc = tid & 15, c_base = tid >> 4;
    #pragma unroll
    for (int s = 0; s < 4; ++s) {
        int c_local = c_base + 16 * s;
        float v0 = Ls[(4 * kc + 0) * 65 + c_local];
        float v1 = Ls[(4 * kc + 1) * 65 + c_local];
        float v2 = Ls[(4 * kc + 2) * 65 + c_local];
        float v3 = Ls[(4 * kc + 3) * 65 + c_local];
        uint2 pk;
        pk.x = bf16pk(v0, v1);
        pk.y = bf16pk(v2, v3);
        *(uint2*)(Wt + (size_t)(half * 256 + c0 + c_local) * FD + k0 + 4 * kc) = pk;
    }
}

// ---------------------------------------------------------------------------
// Kernel 1: C = E @ [W1top|W1bot] + [b1|0] via bf16 MFMA — NO LDS, no barrier.
// (unchanged from R8 — validated). Grid 16x16, 4 waves, K=768 = 24 mfma.
// ---------------------------------------------------------------------------
__global__ __launch_bounds__(256) void gemm_mfma_kernel(
    const ushort* __restrict__ Ebf, const ushort* __restrict__ Wt,
    const float* __restrict__ b1, float* __restrict__ C)
{
    const int tid  = threadIdx.x;
    const int lane = tid & 63, wave = tid >> 6;
    const int wr = wave >> 1, wc = wave & 1;
    const int r0 = blockIdx.y * 32, c0 = blockIdx.x * 32;
    const int n = lane & 15, g = lane >> 4;

    const ushort* aptr = Wt  + (size_t)(c0 + 16 * wc + n) * FD + 8 * g;
    const ushort* bptr = Ebf + (size_t)(r0 + 16 * wr + n) * FD + 8 * g;

    f32x4 acc = {0.f, 0.f, 0.f, 0.f};
    #pragma unroll 8
    for (int ks = 0; ks < 24; ++ks) {
        bf16x8 af = *(const bf16x8*)(aptr + 32 * ks);
        bf16x8 bf = *(const bf16x8*)(bptr + 32 * ks);
        acc = __builtin_amdgcn_mfma_f32_16x16x32_bf16(af, bf, acc, 0, 0, 0);
    }

    const int row = r0 + 16 * wr + n;
    const int col = c0 + 16 * wc + 4 * g;
    float4 b = {0.f, 0.f, 0.f, 0.f};
    if (c0 < 256) b = ((const float4*)b1)[col >> 2];
    float4 o = {acc[0] + b.x, acc[1] + b.y, acc[2] + b.z, acc[3] + b.w};
    *(float4*)&C[(size_t)row * NC + col] = o;
}

// ---------------------------------------------------------------------------
// Kernel 2: pair scores. 16x32 tile, 272 blocks, 128 threads (2 waves),
// 2x2 microtile: 4 ds_read_b128 per k4 for 4 pairs (1.0 instr/pair, was 1.5).
// XOR swizzle key (row>>1)&7 — rows 2t,2t+1 share key: A-reads 4 addrs on 4
// quads, B-reads 16 addrs 2/quad = conflict-free. W2 via uniform s_load.
// ---------------------------------------------------------------------------
__global__ __launch_bounds__(128) void pair_kernel(
    const float* __restrict__ C, const float* __restrict__ W2,
    const float* __restrict__ b2, float* __restrict__ out)
{
    __shared__ float4 As[16 * 64];
    __shared__ float4 Bs[32 * 64];

    int rem = blockIdx.x, bi = 0;
    while (rem >= 16 - (bi >> 1)) { rem -= 16 - (bi >> 1); ++bi; }
    const int bj = (bi >> 1) + rem;
    const int i0 = bi * 16, j0 = bj * 32;

    const int tid = threadIdx.x;
    const float4* C4 = (const float4*)C;        // row pitch 128 f4

    #pragma unroll
    for (int s = 0; s < 8; ++s) {               // A: 16 rows x 64 f4
        int idx = tid + 128 * s;
        int row = idx >> 6, c4 = idx & 63;
        As[row * 64 + (c4 ^ ((row >> 1) & 7))] = C4[(i0 + row) * 128 + c4];
    }
    #pragma unroll
    for (int s = 0; s < 16; ++s) {              // B: 32 rows x 64 f4
        int idx = tid + 128 * s;
        int row = idx >> 6, c4 = idx & 63;
        Bs[row * 64 + (c4 ^ ((row >> 1) & 7))] = C4[(j0 + row) * 128 + 64 + c4];
    }
    __syncthreads();

    const int tx = tid & 15, ty = tid >> 4;     // j-pair 2tx.., i-pair 2ty..
    const int ka = ty & 7, kb = tx & 7;
    const float4* W24 = (const float4*)W2;

    float acc00 = 0.f, acc01 = 0.f, acc10 = 0.f, acc11 = 0.f;
    #pragma unroll 8
    for (int k4 = 0; k4 < HD / 4; ++k4) {
        float4 a0  = As[(2 * ty + 0) * 64 + (k4 ^ ka)];
        float4 a1  = As[(2 * ty + 1) * 64 + (k4 ^ ka)];
        float4 b0  = Bs[(2 * tx + 0) * 64 + (k4 ^ kb)];
        float4 b1v = Bs[(2 * tx + 1) * 64 + (k4 ^ kb)];
        float4 w = W24[k4];                     // uniform -> s_load
        #define PACC(ACC, A, B) \
            ACC = fmaf(fmaxf(A.x + B.x, 0.f), w.x, ACC); \
            ACC = fmaf(fmaxf(A.y + B.y, 0.f), w.y, ACC); \
            ACC = fmaf(fmaxf(A.z + B.z, 0.f), w.z, ACC); \
            ACC = fmaf(fmaxf(A.w + B.w, 0.f), w.w, ACC);
        PACC(acc00, a0, b0) PACC(acc01, a0, b1v)
        PACC(acc10, a1, b0) PACC(acc11, a1, b1v)
        #undef PACC
    }

    const float bias2 = b2[0];
    #pragma unroll
    for (int u = 0; u < 4; ++u) {
        int i = i0 + 2 * ty + (u >> 1);
        int j = j0 + 2 * tx + (u & 1);
        float v = (u == 0) ? acc00 : (u == 1) ? acc01 : (u == 2) ? acc10 : acc11;
        if (j > i) {
            int p = i * (2 * NF - i - 1) / 2 + (j - i - 1);
            out[p]             = (float)i;
            out[PAIRS + p]     = (float)j;
            out[2 * PAIRS + p] = v + bias2;
        }
    }
}

extern "C" void kernel_launch(void* const* d_in, const int* in_sizes, int n_in,
                              void* d_out, int out_size, void* d_ws, size_t ws_size,
                              hipStream_t stream) {
    const float* E  = (const float*)d_in[0];
    const float* W1 = (const float*)d_in[1];
    const float* b1 = (const float*)d_in[2];
    const float* W2 = (const float*)d_in[3];
    const float* b2 = (const float*)d_in[4];
    float* out = (float*)d_out;

    ushort* Ebf = (ushort*)d_ws;                       // 512*768 bf16 (768 KB)
    ushort* Wt  = Ebf + (size_t)NF * FD;               // 512*768 bf16 (768 KB)
    float*  C   = (float*)((char*)d_ws + 2 * (size_t)NF * FD * 2);  // 1 MiB

    prep_kernel<<<576, 256, 0, stream>>>(E, W1, Ebf, Wt);
    gemm_mfma_kernel<<<dim3(16, 16), 256, 0, stream>>>(Ebf, Wt, b1, C);
    pair_kernel<<<272, 128, 0, stream>>>(C, W2, b2, out);
}

// Round 10
// 23.669 us; speedup vs baseline: 1.3130x; 1.3130x over previous
//
#include <hip/hip_runtime.h>

#define FD 768
#define HD 256
#define NF 512
#define NC 512
#define PAIRS (NF * (NF - 1) / 2)   // 130816

typedef __attribute__((ext_vector_type(4))) float f32x4;
typedef __attribute__((ext_vector_type(8))) short bf16x8;

// RNE float->bf16, packed pair (a = low 16, b = high 16)
__device__ inline unsigned bf16pk(float a, float b) {
    unsigned ua = __float_as_uint(a), ub = __float_as_uint(b);
    ua = (ua + 0x7FFFu + ((ua >> 16) & 1u)) >> 16;
    ub = (ub + 0x7FFFu + ((ub >> 16) & 1u)) >> 16;
    return ua | (ub << 16);
}

// ---------------------------------------------------------------------------
// Kernel 1 (R7-validated structure): C = E @ [W1top|W1bot] + [b1|0], bf16
// MFMA, f32 accum. Grid 16x16, 32x32 tile, 4 waves, K=768 in 3 rounds of 256.
// LDS: Et[32r][256k], Wt[32c][256k] bf16, 512B pitch, 16B-granule XOR swizzle.
// ONLY change vs R7: W staging is now coalesced f4 loads (8/thread/round,
// lanes c4=lane&7 -> 128B contiguous) + ds_write_b32 scatter into the SAME
// validated gi-swizzled addresses (banks <=4-way), replacing 32 scalar
// strided global loads per thread per round.
// D layout (validated): lane l, reg p -> C[r0+16wr+(l&15)][c0+16wc+4(l>>4)+p]
// ---------------------------------------------------------------------------
__global__ __launch_bounds__(256) void gemm_mfma_kernel(
    const float* __restrict__ E, const float* __restrict__ W1,
    const float* __restrict__ b1, float* __restrict__ C)
{
    __shared__ char lds[2 * 32 * 512];          // Et 16KB + Wt 16KB
    char* EtB = lds;
    char* WtB = lds + 32 * 512;

    const int tid  = threadIdx.x;
    const int r0   = blockIdx.y * 32, c0 = blockIdx.x * 32;
    const int c0w4 = (c0 & 255) >> 2;           // f4 col offset within W half
    const int dofs = (c0 >= 256) ? FD : 0;
    const int lane = tid & 63, wave = tid >> 6;
    const int wr = wave >> 1, wc = wave & 1;
    const int m = lane & 15, g = lane >> 4;
    const int arow = 16 * wc + m;               // Wt row (= local C col)
    const int brow = 16 * wr + m;               // Et row (= local C row)

    f32x4 acc = {0.f, 0.f, 0.f, 0.f};
    const float4* E4  = (const float4*)E;       // row pitch 192 f4
    const float4* W14 = (const float4*)W1;      // row pitch 64 f4

    for (int rnd = 0; rnd < 3; ++rnd) {
        if (rnd) __syncthreads();               // LDS reuse guard

        // ---- stage Et: 32 rows x 256 k, f4 loads + packed b64 writes ----
        #pragma unroll
        for (int s = 0; s < 8; ++s) {
            int idx = tid + s * 256;            // 2048 f4
            int r = idx >> 6, c4 = idx & 63;    // k = 4*c4
            float4 v = E4[(size_t)(r0 + r) * 192 + rnd * 64 + c4];
            uint2 pk;
            pk.x = bf16pk(v.x, v.y);
            pk.y = bf16pk(v.z, v.w);
            int gi = (c4 >> 1) ^ (r & 7);
            *(uint2*)(EtB + r * 512 + gi * 16 + (c4 & 1) * 8) = pk;
        }
        // ---- stage Wt: coalesced f4 loads + b32 scatter (R7 addresses) ----
        #pragma unroll
        for (int it2 = 0; it2 < 4; ++it2) {
            int task = it2 * 256 + tid;         // 1024 = 8 c-quads x 128 kp
            int c4 = task & 7, kp = task >> 3;
            int d = dofs + rnd * 256 + 2 * kp;
            float4 w0 = W14[(size_t)d * 64 + c0w4 + c4];
            float4 w1 = W14[(size_t)(d + 1) * 64 + c0w4 + c4];
            float a0v[4] = {w0.x, w0.y, w0.z, w0.w};
            float a1v[4] = {w1.x, w1.y, w1.z, w1.w};
            #pragma unroll
            for (int u = 0; u < 4; ++u) {
                int c = 4 * c4 + u;
                unsigned pk = bf16pk(a0v[u], a1v[u]);
                int gi = (kp >> 2) ^ (c & 7);
                *(unsigned*)(WtB + c * 512 + gi * 16 + (kp & 3) * 4) = pk;
            }
        }
        __syncthreads();

        // ---- 8 mfma per wave (K chunk = 256) ----
        #pragma unroll
        for (int ks = 0; ks < 8; ++ks) {
            int giA = (4 * ks + g) ^ (arow & 7);
            int giB = (4 * ks + g) ^ (brow & 7);
            bf16x8 af = *(const bf16x8*)(WtB + arow * 512 + giA * 16);
            bf16x8 bf = *(const bf16x8*)(EtB + brow * 512 + giB * 16);
            acc = __builtin_amdgcn_mfma_f32_16x16x32_bf16(af, bf, acc, 0, 0, 0);
        }
    }

    const int row = r0 + 16 * wr + m;           // n = l&15
    const int col = c0 + 16 * wc + 4 * g;       // m = 4*(l>>4)+p
    float4 b = {0.f, 0.f, 0.f, 0.f};
    if (c0 < 256) b = ((const float4*)b1)[col >> 2];
    float4 o = {acc[0] + b.x, acc[1] + b.y, acc[2] + b.z, acc[3] + b.w};
    *(float4*)&C[(size_t)row * NC + col] = o;
}

// ---------------------------------------------------------------------------
// Kernel 2: pair scores (EXACT R7 code — validated twice at absmax 0.0156).
// 16x32 tile, 272 blocks, 256 thr, 1x2 micro. XOR-swizzled LDS; W2 s_load.
// ---------------------------------------------------------------------------
__global__ __launch_bounds__(256) void pair_kernel(
    const float* __restrict__ C, const float* __restrict__ W2,
    const float* __restrict__ b2, float* __restrict__ out)
{
    __shared__ float4 As[16 * 64];
    __shared__ float4 Bs[32 * 64];

    int rem = blockIdx.x, bi = 0;
    while (rem >= 16 - (bi >> 1)) { rem -= 16 - (bi >> 1); ++bi; }
    const int bj = (bi >> 1) + rem;
    const int i0 = bi * 16, j0 = bj * 32;

    const int tid = threadIdx.x;
    const float4* C4 = (const float4*)C;        // row pitch 128 f4

    #pragma unroll
    for (int s = 0; s < 4; ++s) {               // A: 16 rows x 64 f4
        int idx = tid + 256 * s;
        int row = idx >> 6, c4 = idx & 63;
        As[row * 64 + (c4 ^ ((row >> 1) & 7))] = C4[(i0 + row) * 128 + c4];
    }
    #pragma unroll
    for (int s = 0; s < 8; ++s) {               // B: 32 rows x 64 f4
        int idx = tid + 256 * s;
        int row = idx >> 6, c4 = idx & 63;
        Bs[row * 64 + (c4 ^ ((row >> 1) & 7))] = C4[(j0 + row) * 128 + 64 + c4];
    }
    __syncthreads();

    const int tx = tid & 15, ty = tid >> 4;
    const int keyA = (ty >> 1) & 7, keyB = tx & 7;
    const float4* W24 = (const float4*)W2;

    float acc0 = 0.f, acc1 = 0.f;
    #pragma unroll 8
    for (int k4 = 0; k4 < HD / 4; ++k4) {
        float4 a   = As[ty * 64 + (k4 ^ keyA)];
        float4 b0  = Bs[(2 * tx + 0) * 64 + (k4 ^ keyB)];
        float4 b1v = Bs[(2 * tx + 1) * 64 + (k4 ^ keyB)];
        float4 w = W24[k4];                     // uniform -> s_load
        acc0 = fmaf(fmaxf(a.x + b0.x, 0.f), w.x, acc0);
        acc0 = fmaf(fmaxf(a.y + b0.y, 0.f), w.y, acc0);
        acc0 = fmaf(fmaxf(a.z + b0.z, 0.f), w.z, acc0);
        acc0 = fmaf(fmaxf(a.w + b0.w, 0.f), w.w, acc0);
        acc1 = fmaf(fmaxf(a.x + b1v.x, 0.f), w.x, acc1);
        acc1 = fmaf(fmaxf(a.y + b1v.y, 0.f), w.y, acc1);
        acc1 = fmaf(fmaxf(a.z + b1v.z, 0.f), w.z, acc1);
        acc1 = fmaf(fmaxf(a.w + b1v.w, 0.f), w.w, acc1);
    }

    const float bias2 = b2[0];
    const int i = i0 + ty;
    #pragma unroll
    for (int u = 0; u < 2; ++u) {
        int j = j0 + 2 * tx + u;
        float v = u ? acc1 : acc0;
        if (j > i) {
            int p = i * (2 * NF - i - 1) / 2 + (j - i - 1);
            out[p]             = (float)i;
            out[PAIRS + p]     = (float)j;
            out[2 * PAIRS + p] = v + bias2;
        }
    }
}

extern "C" void kernel_launch(void* const* d_in, const int* in_sizes, int n_in,
                              void* d_out, int out_size, void* d_ws, size_t ws_size,
                              hipStream_t stream) {
    const float* E  = (const float*)d_in[0];
    const float* W1 = (const float*)d_in[1];
    const float* b1 = (const float*)d_in[2];
    const float* W2 = (const float*)d_in[3];
    const float* b2 = (const float*)d_in[4];
    float* out = (float*)d_out;
    float* C   = (float*)d_ws;                  // 1 MiB

    gemm_mfma_kernel<<<dim3(16, 16), 256, 0, stream>>>(E, W1, b1, C);
    pair_kernel<<<272, 256, 0, stream>>>(C, W2, b2, out);
}